// Round 13
// baseline (3000.721 us; speedup 1.0000x reference)
//
#include <hip/hip_runtime.h>
#include <stdint.h>

typedef __bf16 bf16;
typedef bf16 bf16x8 __attribute__((ext_vector_type(8)));
typedef float f32x4 __attribute__((ext_vector_type(4)));
typedef uint32_t u32;
typedef unsigned long long u64;
typedef unsigned char u8;

#define NN   4096
#define HID  256
#define NCLS 128

__device__ __forceinline__ void gload16(const void* g, void* l) {
  __builtin_amdgcn_global_load_lds((const __attribute__((address_space(1))) u32*)g,
                                   (__attribute__((address_space(3))) u32*)l, 16, 0, 0);
}

// f32 -> bf16, n % 4 == 0
__global__ void convf2b(const float* __restrict__ s, bf16* __restrict__ d, int n) {
  int i = (blockIdx.x * blockDim.x + threadIdx.x) * 4;
  if (i >= n) return;
  f32x4 v = *(const f32x4*)(s + i);
  bf16 o[4] = {(bf16)v[0], (bf16)v[1], (bf16)v[2], (bf16)v[3]};
  *(u64*)(d + i) = *(u64*)o;
}

// f32 -> fp8 e4m3 scaled by 2^12 (A entries uniform [0, 2^-12])
__global__ void convAf8(const float* __restrict__ s, u8* __restrict__ d, int n) {
  int i = (blockIdx.x * blockDim.x + threadIdx.x) * 4;
  if (i >= n) return;
  f32x4 v = *(const f32x4*)(s + i);
  u32 pk = __builtin_amdgcn_cvt_pk_fp8_f32(v[0] * 4096.f, v[1] * 4096.f, 0, false);
  pk = __builtin_amdgcn_cvt_pk_fp8_f32(v[2] * 4096.f, v[3] * 4096.f, pk, true);
  *(u32*)(d + i) = pk;
}

// K-split reduce: 24 slabs [16][17] f32. Wave (kw,sw) owns quadrant (kw>>1, kw&1).
// All acc[][] indices compile-time (rule #20 — R5/R6 scratch-spill lesson).
__device__ __forceinline__ f32x4 ksplit_reduce(char* smem, f32x4 acc[2][2],
                                               int kw, int sw, int hh, int rl) {
  float* fs = (float*)smem;
  #pragma unroll
  for (int q = 0; q < 4; ++q) {
    const int src = (kw < q) ? kw : kw - 1;
    float* dst = fs + ((q * 3 + src) * 2 + sw) * 272;
    const int mf = q >> 1, nf = q & 1;
    if (q != kw) {
      #pragma unroll
      for (int j = 0; j < 4; ++j) dst[(hh * 4 + j) * 17 + rl] = acc[mf][nf][j];
    }
  }
  asm volatile("s_waitcnt lgkmcnt(0)" ::: "memory");
  __builtin_amdgcn_s_barrier();
  f32x4 r;
  if (kw == 0)      r = acc[0][0];
  else if (kw == 1) r = acc[0][1];
  else if (kw == 2) r = acc[1][0];
  else              r = acc[1][1];
  #pragma unroll
  for (int src = 0; src < 3; ++src) {
    const float* sp = fs + ((kw * 3 + src) * 2 + sw) * 272;
    #pragma unroll
    for (int j = 0; j < 4; ++j) r[j] += sp[(hh * 4 + j) * 17 + rl];
  }
  return r;
}

// ---------------- big GEMM: C = (A_fp8 @ y^T_fp8) * 2^-12, bf16 out ----------------
// 64x32 tile, grid 512 (2 blocks/CU). 8 waves = 2 m-halves x 4 K-split.
// A: direct global->VGPR (no LDS transit), distance-1 double-buffered named regs.
// B: LDS-staged (8x wave reuse), all 8 waves stage 1KB/round, depth-3 (24KB).
// Macro K-step 256B, 16 rounds. Steady-state vmcnt(1): per round issues
// [4xA-global, 1xB-gload] -> at round t only B(t+1) is newer than A(t).
__global__ __launch_bounds__(512, 2) void gemmf8(
    const u8* __restrict__ Ag,   // [4096][4096] fp8 = A * 2^12
    const u8* __restrict__ Bg,   // [256][4096]  fp8 = y^T
    bf16* __restrict__ Cb)       // [4096][256]  bf16
{
  __shared__ __align__(16) char smem[28672];   // 3 B-bufs x 8KB; reduce reuses
  const int tid = threadIdx.x;
  const int l = tid & 63, wv = tid >> 6;
  const int kw = wv & 3, sw = wv >> 2;
  const int rl = l & 15, hh = l >> 4;

  const int chunk = gridDim.x >> 3;            // 64
  const int sb = (blockIdx.x & 7) * chunk + (blockIdx.x >> 3);
  const int m0 = (sb >> 3) * 64, n0 = (sb & 7) * 32;

  // ---- B staging: wave wv stages rows n0+wv*4+{0..3}, 1 gload16 per round ----
  const int rlo = l >> 4, gq = l & 15;
  const int brow = wv * 4 + rlo;
  const u8* srcB = Bg + (size_t)(n0 + brow) * 4096 + ((gq ^ (brow & 7)) << 4);

  // ---- A direct: lane reads 8B at row*4096 + t*256 + kw*64 + ks*32 + hh*8 ----
  const u8* pa0 = Ag + (size_t)(m0 + sw * 32 + rl) * 4096 + kw * 64 + hh * 8;
  const u8* pa1 = pa0 + (size_t)16 * 4096;

  f32x4 acc[2][2];
  #pragma unroll
  for (int i = 0; i < 2; ++i)
    #pragma unroll
    for (int j = 0; j < 2; ++j) acc[i][j] = (f32x4){0.f, 0.f, 0.f, 0.f};

  u64 Ar[2][4];                                // [t&1][a0k0, a0k1, a1k0, a1k1]

  // prologue: A(0), B(0), B(1)  ->  steady-state vmcnt(1) holds from round 0
  Ar[0][0] = *(const u64*)(pa0);
  Ar[0][1] = *(const u64*)(pa0 + 32);
  Ar[0][2] = *(const u64*)(pa1);
  Ar[0][3] = *(const u64*)(pa1 + 32);
  gload16(srcB,       smem + wv * 1024);
  gload16(srcB + 256, smem + 8192 + wv * 1024);

  #pragma unroll
  for (int t = 0; t < 16; ++t) {
    if (t < 15) { asm volatile("s_waitcnt vmcnt(1)" ::: "memory"); }
    else        { asm volatile("s_waitcnt vmcnt(0)" ::: "memory"); }
    __builtin_amdgcn_sched_barrier(0);
    __builtin_amdgcn_s_barrier();
    __builtin_amdgcn_sched_barrier(0);
    if (t + 1 < 16) {                          // A(t+1) -> other reg set
      const u8* qa0 = pa0 + (t + 1) * 256;
      const u8* qa1 = pa1 + (t + 1) * 256;
      Ar[(t + 1) & 1][0] = *(const u64*)(qa0);
      Ar[(t + 1) & 1][1] = *(const u64*)(qa0 + 32);
      Ar[(t + 1) & 1][2] = *(const u64*)(qa1);
      Ar[(t + 1) & 1][3] = *(const u64*)(qa1 + 32);
    }
    if (t + 2 < 16)                            // B(t+2) -> buf (t+2)%3
      gload16(srcB + (t + 2) * 256, smem + ((t + 2) % 3) * 8192 + wv * 1024);

    const char* Bs = smem + (t % 3) * 8192;
    #pragma unroll
    for (int ks = 0; ks < 2; ++ks) {
      const int g0 = kw * 4 + ks * 2 + (hh >> 1);
      const int co = ((g0 ^ (rl & 7)) << 4) + (hh & 1) * 8;
      u64 b0 = *(const u64*)(Bs + (rl +  0) * 256 + co);
      u64 b1 = *(const u64*)(Bs + (rl + 16) * 256 + co);
      const u64 a0 = Ar[t & 1][ks];
      const u64 a1 = Ar[t & 1][2 + ks];
      __builtin_amdgcn_s_setprio(1);
      acc[0][0] = __builtin_amdgcn_mfma_f32_16x16x32_fp8_fp8((long)a0, (long)b0, acc[0][0], 0, 0, 0);
      acc[0][1] = __builtin_amdgcn_mfma_f32_16x16x32_fp8_fp8((long)a0, (long)b1, acc[0][1], 0, 0, 0);
      acc[1][0] = __builtin_amdgcn_mfma_f32_16x16x32_fp8_fp8((long)a1, (long)b0, acc[1][0], 0, 0, 0);
      acc[1][1] = __builtin_amdgcn_mfma_f32_16x16x32_fp8_fp8((long)a1, (long)b1, acc[1][1], 0, 0, 0);
      __builtin_amdgcn_s_setprio(0);
    }
  }
  __builtin_amdgcn_s_barrier();
  __builtin_amdgcn_sched_barrier(0);

  f32x4 o = ksplit_reduce(smem, acc, kw, sw, hh, rl);
  const int row0 = m0 + sw * 32 + (kw >> 1) * 16 + hh * 4;
  const int col  = n0 + (kw & 1) * 16 + rl;
  #pragma unroll
  for (int r = 0; r < 4; ++r)
    Cb[(row0 + r) * HID + col] = (bf16)(o[r] * 2.44140625e-4f);
}

// ---------------- bf16 GEMM: 64x32 tile, 2 blocks/CU ----------------
// KK==256: single-shot staging (whole K in LDS: A 32KB + B 16KB), one barrier.
// KK==512: 2-buf pipelined loop (EPI1 only).
// EPI: 1=tanh->bf16  2=h init (xs,traj0,Y8)  3..6=k1..k4 RK4  7=f32 out+bias
template<int EPI, int KK>
__global__ __launch_bounds__(512, 2) void gemmbf(
    const bf16* __restrict__ Ag, int lda,
    const bf16* __restrict__ Bg, int ldb,
    int Ntiles,
    const float* __restrict__ bias,
    float* __restrict__ outf,
    bf16* __restrict__ outb,
    u8* __restrict__ ybt,                 // fp8 y^T [HID][NN]
    float* __restrict__ xbuf,
    const float* __restrict__ kk1,
    const float* __restrict__ kk2,
    const float* __restrict__ kk3,
    const float* __restrict__ vt, int step)
{
  __shared__ __align__(16) char smem[49152];
  const int tid = threadIdx.x;
  const int l = tid & 63, wv = tid >> 6;
  const int kw = wv & 3, sw = wv >> 2;
  const int rl = l & 15, hh = l >> 4;

  const int chunk = gridDim.x >> 3;
  const int sb = (blockIdx.x & 7) * chunk + (blockIdx.x >> 3);
  const int mtile = sb / Ntiles;
  const int ntile = sb - mtile * Ntiles;
  const int m0 = mtile * 64, n0 = ntile * 32;

  const bool isB = wv >= 4;
  const int w4 = wv & 3;

  f32x4 acc[2][2];
  #pragma unroll
  for (int i = 0; i < 2; ++i)
    #pragma unroll
    for (int j = 0; j < 2; ++j) acc[i][j] = (f32x4){0.f, 0.f, 0.f, 0.f};

  if constexpr (KK == 256) {
    // ---- single-shot: LDS A [64][512B] @0, B [32][512B] @32768 (verified R8) ----
    const int lrow = l >> 5, lg = l & 31;
    if (!isB) {
      const char* gb = (const char*)(Ag + (size_t)(m0 + w4 * 16) * lda);
      char* base = smem + w4 * 8192;
      #pragma unroll
      for (int i = 0; i < 8; ++i) {
        const int r = i * 2 + lrow;                  // local row within 16
        const int swz = (lg ^ ((w4 * 16 + r) & 7)) << 4;
        gload16(gb + (size_t)r * lda * 2 + swz, base + i * 1024);
      }
    } else {
      const char* gb = (const char*)(Bg + (size_t)(n0 + w4 * 8) * ldb);
      char* base = smem + 32768 + w4 * 4096;
      #pragma unroll
      for (int i = 0; i < 4; ++i) {
        const int r = i * 2 + lrow;                  // local row within 8
        const int swz = (lg ^ ((w4 * 8 + r) & 7)) << 4;
        gload16(gb + (size_t)r * ldb * 2 + swz, base + i * 1024);
      }
    }
    asm volatile("s_waitcnt vmcnt(0)" ::: "memory");
    __builtin_amdgcn_sched_barrier(0);
    __builtin_amdgcn_s_barrier();
    __builtin_amdgcn_sched_barrier(0);

    const char* As = smem;
    const char* Bs = smem + 32768;
    #pragma unroll
    for (int ks = 0; ks < 2; ++ks) {
      const int ca = ((((kw * 2 + ks) * 4 + hh) ^ (rl & 7)) << 4);
      bf16x8 a0 = *(const bf16x8*)(As + (sw * 32 + rl +  0) * 512 + ca);
      bf16x8 a1 = *(const bf16x8*)(As + (sw * 32 + rl + 16) * 512 + ca);
      bf16x8 b0 = *(const bf16x8*)(Bs + (rl +  0) * 512 + ca);
      bf16x8 b1 = *(const bf16x8*)(Bs + (rl + 16) * 512 + ca);
      __builtin_amdgcn_s_setprio(1);
      acc[0][0] = __builtin_amdgcn_mfma_f32_16x16x32_bf16(a0, b0, acc[0][0], 0, 0, 0);
      acc[0][1] = __builtin_amdgcn_mfma_f32_16x16x32_bf16(a0, b1, acc[0][1], 0, 0, 0);
      acc[1][0] = __builtin_amdgcn_mfma_f32_16x16x32_bf16(a1, b0, acc[1][0], 0, 0, 0);
      acc[1][1] = __builtin_amdgcn_mfma_f32_16x16x32_bf16(a1, b1, acc[1][1], 0, 0, 0);
      __builtin_amdgcn_s_setprio(0);
    }
    __builtin_amdgcn_s_barrier();
    __builtin_amdgcn_sched_barrier(0);
  } else {
    // ---- pipelined 2-buf loop (macro 128 elems = 256B) ----
    const int rlo = l >> 4, gq = l & 15;
    const size_t ldby = (size_t)(isB ? ldb : lda) * 2;
    const int grow = (isB ? n0 + w4 * 8 : m0 + w4 * 16) + rlo;
    const char* sGb = (const char*)(isB ? (const void*)Bg : (const void*)Ag)
                      + (size_t)grow * ldby;
    const int c0 = (gq ^ rlo) << 4;
    const int c1 = (gq ^ (rlo + 4)) << 4;
    const int stoff = isB ? 16384 + w4 * 2048 : w4 * 4096;

    auto stage = [&](int buf, int t) {
      char* base = smem + buf * 24576 + stoff;
      const char* g = sGb + (size_t)t * 256;
      gload16(g + c0,            base);
      gload16(g + 4 * ldby + c1, base + 1024);
      if (!isB) {
        gload16(g +  8 * ldby + c0, base + 2048);
        gload16(g + 12 * ldby + c1, base + 3072);
      }
    };

    const int ca = ((kw * 4 + hh) ^ (rl & 7)) << 4;
    auto compute = [&](int buf) {
      const char* As = smem + buf * 24576;
      const char* Bs = As + 16384;
      bf16x8 a0 = *(const bf16x8*)(As + (sw * 32 + rl +  0) * 256 + ca);
      bf16x8 a1 = *(const bf16x8*)(As + (sw * 32 + rl + 16) * 256 + ca);
      bf16x8 b0 = *(const bf16x8*)(Bs + (rl +  0) * 256 + ca);
      bf16x8 b1 = *(const bf16x8*)(Bs + (rl + 16) * 256 + ca);
      __builtin_amdgcn_s_setprio(1);
      acc[0][0] = __builtin_amdgcn_mfma_f32_16x16x32_bf16(a0, b0, acc[0][0], 0, 0, 0);
      acc[0][1] = __builtin_amdgcn_mfma_f32_16x16x32_bf16(a0, b1, acc[0][1], 0, 0, 0);
      acc[1][0] = __builtin_amdgcn_mfma_f32_16x16x32_bf16(a1, b0, acc[1][0], 0, 0, 0);
      acc[1][1] = __builtin_amdgcn_mfma_f32_16x16x32_bf16(a1, b1, acc[1][1], 0, 0, 0);
      __builtin_amdgcn_s_setprio(0);
    };

    const int nmac = KK >> 7;
    stage(0, 0);
    asm volatile("s_waitcnt vmcnt(0)" ::: "memory");
    __builtin_amdgcn_s_barrier();
    int cur = 0;
    for (int t = 0; t < nmac; ++t) {
      if (t + 1 < nmac) stage(cur ^ 1, t + 1);
      compute(cur);
      asm volatile("s_waitcnt vmcnt(0)" ::: "memory");
      __builtin_amdgcn_sched_barrier(0);
      __builtin_amdgcn_s_barrier();
      cur ^= 1;
    }
    __builtin_amdgcn_sched_barrier(0);
  }

  f32x4 o = ksplit_reduce(smem, acc, kw, sw, hh, rl);
  const int row0 = m0 + sw * 32 + (kw >> 1) * 16 + hh * 4;
  const int col  = n0 + (kw & 1) * 16 + rl;

  float dtv = 0.f;
  if constexpr (EPI >= 3 && EPI <= 6) dtv = vt[step + 1] - vt[step];

  if constexpr (EPI == 1) {
    #pragma unroll
    for (int r = 0; r < 4; ++r)
      outb[(row0 + r) * HID + col] = (bf16)tanhf(o[r] + bias[col]);
  } else if constexpr (EPI == 2) {
    float yv[4];
    #pragma unroll
    for (int r = 0; r < 4; ++r) {
      float v = o[r] + bias[col];
      xbuf[(row0 + r) * HID + col] = v;
      outb[(row0 + r) * HID + col] = (bf16)v;
      yv[r] = v;
    }
    u32 pk = __builtin_amdgcn_cvt_pk_fp8_f32(yv[0], yv[1], 0, false);
    pk = __builtin_amdgcn_cvt_pk_fp8_f32(yv[2], yv[3], pk, true);
    *(u32*)(ybt + (size_t)col * NN + row0) = pk;
  } else if constexpr (EPI >= 3 && EPI <= 6) {
    float yv[4];
    #pragma unroll
    for (int r = 0; r < 4; ++r) {
      const int idx = (row0 + r) * HID + col;
      float v = fmaxf(o[r] + bias[col], 0.f);   // k_p
      float xv = xbuf[idx];
      float y;
      if constexpr (EPI == 3)      { outf[idx] = v; y = xv + dtv * (1.f/3.f) * v; }
      else if constexpr (EPI == 4) { outf[idx] = v; y = xv + dtv * (v - kk1[idx] * (1.f/3.f)); }
      else if constexpr (EPI == 5) { outf[idx] = v; y = xv + dtv * (kk1[idx] - kk2[idx] + v); }
      else {
        float xn = xv + dtv * 0.125f * (kk1[idx] + 3.f*kk2[idx] + 3.f*kk3[idx] + v);
        xbuf[idx] = xn;
        outb[idx] = (bf16)xn;   // traj slot t+1
        y = xn;
      }
      yv[r] = y;
    }
    u32 pk = __builtin_amdgcn_cvt_pk_fp8_f32(yv[0], yv[1], 0, false);
    pk = __builtin_amdgcn_cvt_pk_fp8_f32(yv[2], yv[3], pk, true);
    *(u32*)(ybt + (size_t)col * NN + row0) = pk;
  } else { // EPI == 7
    #pragma unroll
    for (int r = 0; r < 4; ++r)
      outf[(size_t)(row0 + r) * NCLS + col] = o[r] + bias[col];
  }
}

extern "C" void kernel_launch(void* const* d_in, const int* in_sizes, int n_in,
                              void* d_out, int out_size, void* d_ws, size_t ws_size,
                              hipStream_t stream)
{
  const float* vt = (const float*)d_in[0];
  const float* x  = (const float*)d_in[1];
  const float* A  = (const float*)d_in[2];
  const float* W1 = (const float*)d_in[3];
  const float* b1 = (const float*)d_in[4];
  const float* W2 = (const float*)d_in[5];
  const float* b2 = (const float*)d_in[6];
  const float* Wt = (const float*)d_in[7];
  const float* bt = (const float*)d_in[8];
  const float* Wo = (const float*)d_in[9];
  const float* bo = (const float*)d_in[10];
  float* out = (float*)d_out;

  char* p = (char*)d_ws;
  auto carve = [&](size_t n) { char* r = p; p += (n + 255) & ~(size_t)255; return r; };
  u8*   A8  = (u8*)carve((size_t)4096 * 4096);        // fp8 A * 2^12
  bf16* xb  = (bf16*)carve((size_t)4096 * 512 * 2);
  bf16* W1b = (bf16*)carve((size_t)256 * 512 * 2);
  bf16* W2b = (bf16*)carve((size_t)256 * 256 * 2);
  bf16* Wtb = (bf16*)carve((size_t)256 * 256 * 2);
  bf16* Wob = (bf16*)carve((size_t)128 * 256 * 2);
  bf16* T1b = (bf16*)carve((size_t)4096 * 256 * 2);
  bf16* Cb  = (bf16*)carve((size_t)4096 * 256 * 2);
  u8*   Y8  = (u8*)carve((size_t)256 * 4096);         // fp8 y^T [HID][NN]
  float* xs = (float*)carve((size_t)4096 * 256 * 4);
  float* k1 = (float*)carve((size_t)4096 * 256 * 4);
  float* k2 = (float*)carve((size_t)4096 * 256 * 4);
  float* k3 = (float*)carve((size_t)4096 * 256 * 4);
  size_t base_need = (size_t)(p - (char*)d_ws);
  const size_t trajBytes = (size_t)20 * 4096 * 256 * 2;
  bool big = (ws_size >= base_need + trajBytes);
  bf16* traj = (bf16*)carve(big ? trajBytes : (size_t)4096 * 256 * 2);

  convAf8<<<16384, 256, 0, stream>>>(A,  A8,  16777216);
  convf2b<<<2048,  256, 0, stream>>>(x,  xb,  2097152);
  convf2b<<<128,   256, 0, stream>>>(W1, W1b, 131072);
  convf2b<<<64,    256, 0, stream>>>(W2, W2b, 65536);
  convf2b<<<64,    256, 0, stream>>>(Wt, Wtb, 65536);
  convf2b<<<32,    256, 0, stream>>>(Wo, Wob, 32768);

  gemmbf<1, 512><<<512, 512, 0, stream>>>(xb, 512, W1b, 512, 8, b1,
      nullptr, T1b, nullptr, nullptr, nullptr, nullptr, nullptr, vt, 0);
  gemmbf<2, 256><<<512, 512, 0, stream>>>(T1b, 256, W2b, 256, 8, b2,
      nullptr, traj, Y8, xs, nullptr, nullptr, nullptr, vt, 0);
  if (!big)
    gemmbf<7, 256><<<256, 512, 0, stream>>>(traj, 256, Wob, 256, 4, bo,
        out, nullptr, nullptr, nullptr, nullptr, nullptr, nullptr, vt, 0);

  for (int t = 0; t < 19; ++t) {
    bf16* slot = big ? (traj + (size_t)(t + 1) * 4096 * 256) : traj;
    gemmf8<<<512, 512, 0, stream>>>(A8, Y8, Cb);
    gemmbf<3, 256><<<512, 512, 0, stream>>>(Cb, 256, Wtb, 256, 8, bt,
        k1, nullptr, Y8, xs, nullptr, nullptr, nullptr, vt, t);
    gemmf8<<<512, 512, 0, stream>>>(A8, Y8, Cb);
    gemmbf<4, 256><<<512, 512, 0, stream>>>(Cb, 256, Wtb, 256, 8, bt,
        k2, nullptr, Y8, xs, k1, nullptr, nullptr, vt, t);
    gemmf8<<<512, 512, 0, stream>>>(A8, Y8, Cb);
    gemmbf<5, 256><<<512, 512, 0, stream>>>(Cb, 256, Wtb, 256, 8, bt,
        k3, nullptr, Y8, xs, k1, k2, nullptr, vt, t);
    gemmf8<<<512, 512, 0, stream>>>(A8, Y8, Cb);
    gemmbf<6, 256><<<512, 512, 0, stream>>>(Cb, 256, Wtb, 256, 8, bt,
        nullptr, slot, Y8, xs, k1, k2, k3, vt, t);
    if (!big)
      gemmbf<7, 256><<<256, 512, 0, stream>>>(traj, 256, Wob, 256, 4, bo,
          out + (size_t)(t + 1) * 4096 * 128, nullptr, nullptr, nullptr,
          nullptr, nullptr, nullptr, vt, 0);
  }
  if (big)
    gemmbf<7, 256><<<5120, 512, 0, stream>>>(traj, 256, Wob, 256, 4, bo,
        out, nullptr, nullptr, nullptr, nullptr, nullptr, nullptr, vt, 0);
}

// Round 14
// 1433.050 us; speedup vs baseline: 2.0939x; 2.0939x over previous
//
#include <hip/hip_runtime.h>
#include <stdint.h>

typedef __bf16 bf16;
typedef bf16 bf16x8 __attribute__((ext_vector_type(8)));
typedef float f32x4 __attribute__((ext_vector_type(4)));
typedef uint32_t u32;
typedef unsigned long long u64;
typedef unsigned char u8;

#define NN   4096
#define HID  256
#define NCLS 128

__device__ __forceinline__ void gload16(const void* g, void* l) {
  __builtin_amdgcn_global_load_lds((const __attribute__((address_space(1))) u32*)g,
                                   (__attribute__((address_space(3))) u32*)l, 16, 0, 0);
}

// f32 -> bf16, n % 4 == 0
__global__ void convf2b(const float* __restrict__ s, bf16* __restrict__ d, int n) {
  int i = (blockIdx.x * blockDim.x + threadIdx.x) * 4;
  if (i >= n) return;
  f32x4 v = *(const f32x4*)(s + i);
  bf16 o[4] = {(bf16)v[0], (bf16)v[1], (bf16)v[2], (bf16)v[3]};
  *(u64*)(d + i) = *(u64*)o;
}

// f32 -> fp8 e4m3 scaled by 2^12 (A entries uniform [0, 2^-12])
__global__ void convAf8(const float* __restrict__ s, u8* __restrict__ d, int n) {
  int i = (blockIdx.x * blockDim.x + threadIdx.x) * 4;
  if (i >= n) return;
  f32x4 v = *(const f32x4*)(s + i);
  u32 pk = __builtin_amdgcn_cvt_pk_fp8_f32(v[0] * 4096.f, v[1] * 4096.f, 0, false);
  pk = __builtin_amdgcn_cvt_pk_fp8_f32(v[2] * 4096.f, v[3] * 4096.f, pk, true);
  *(u32*)(d + i) = pk;
}

// K-split reduce: 24 slabs [16][17] f32. Wave (kw,sw) owns quadrant (kw>>1, kw&1).
// All acc[][] indices compile-time (rule #20 — R5/R6 scratch-spill lesson).
__device__ __forceinline__ f32x4 ksplit_reduce(char* smem, f32x4 acc[2][2],
                                               int kw, int sw, int hh, int rl) {
  float* fs = (float*)smem;
  #pragma unroll
  for (int q = 0; q < 4; ++q) {
    const int src = (kw < q) ? kw : kw - 1;
    float* dst = fs + ((q * 3 + src) * 2 + sw) * 272;
    const int mf = q >> 1, nf = q & 1;
    if (q != kw) {
      #pragma unroll
      for (int j = 0; j < 4; ++j) dst[(hh * 4 + j) * 17 + rl] = acc[mf][nf][j];
    }
  }
  asm volatile("s_waitcnt lgkmcnt(0)" ::: "memory");
  __builtin_amdgcn_s_barrier();
  f32x4 r;
  if (kw == 0)      r = acc[0][0];
  else if (kw == 1) r = acc[0][1];
  else if (kw == 2) r = acc[1][0];
  else              r = acc[1][1];
  #pragma unroll
  for (int src = 0; src < 3; ++src) {
    const float* sp = fs + ((kw * 3 + src) * 2 + sw) * 272;
    #pragma unroll
    for (int j = 0; j < 4; ++j) r[j] += sp[(hh * 4 + j) * 17 + rl];
  }
  return r;
}

// ---------------- big GEMM: C = (A_fp8 @ y^T_fp8) * 2^-12, bf16 out ----------------
// R9 config (best): 64x32 tile, grid 512 (2 blocks/CU). 8 waves = 2 m-halves x 4 K-split.
// Macro K-step 256B: 16 rounds, 8 MFMA + 8 ds_read per round per wave.
// Depth-3 LDS pipeline (72KB x2 = 144KB/CU), distance-2, counted vmcnt.
__global__ __launch_bounds__(512, 2) void gemmf8(
    const u8* __restrict__ Ag,   // [4096][4096] fp8 = A * 2^12
    const u8* __restrict__ Bg,   // [256][4096]  fp8 = y^T
    bf16* __restrict__ Cb)       // [4096][256]  bf16
{
  __shared__ __align__(16) char smem[73728];   // 3 bufs x (A 16KB | B 8KB)
  const int tid = threadIdx.x;
  const int l = tid & 63, wv = tid >> 6;
  const int kw = wv & 3, sw = wv >> 2;
  const int rl = l & 15, hh = l >> 4;

  const int chunk = gridDim.x >> 3;            // 64
  const int sb = (blockIdx.x & 7) * chunk + (blockIdx.x >> 3);
  const int m0 = (sb >> 3) * 64, n0 = (sb & 7) * 32;

  // staging: waves 0-3 stage A (16 rows, 4 loads), waves 4-7 stage B (8 rows, 2 loads)
  const bool isB = wv >= 4;
  const int w4 = wv & 3;
  const int rlo = l >> 4;                      // row-in-4 per gload group
  const int gq = l & 15;                       // granule slot 0..15
  const int rowbase = isB ? n0 + w4 * 8 : m0 + w4 * 16;
  const u8* sGbase = (isB ? Bg : Ag) + (size_t)rowbase * 4096;
  const int c0 = (gq ^ rlo) << 4;              // src granule, rows r%8 in {0..3}
  const int c1 = (gq ^ (rlo + 4)) << 4;        // rows r%8 in {4..7}
  const int stoff = isB ? 16384 + w4 * 2048 : w4 * 4096;

  f32x4 acc[2][2];
  #pragma unroll
  for (int i = 0; i < 2; ++i)
    #pragma unroll
    for (int j = 0; j < 2; ++j) acc[i][j] = (f32x4){0.f, 0.f, 0.f, 0.f};

  auto stage = [&](int buf, int t) {
    char* base = smem + buf * 24576 + stoff;
    const u8* g = sGbase + (size_t)rlo * 4096 + t * 256;
    gload16(g + c0,                      base);
    gload16(g + (size_t)4  * 4096 + c1,  base + 1024);
    if (!isB) {
      gload16(g + (size_t)8  * 4096 + c0, base + 2048);
      gload16(g + (size_t)12 * 4096 + c1, base + 3072);
    }
  };

  auto compute = [&](int buf) {
    const char* As = smem + buf * 24576;
    const char* Bs = As + 16384;
    #pragma unroll
    for (int ks = 0; ks < 2; ++ks) {
      const int g0 = (kw * 2 + ks) * 2 + (hh >> 1);          // granule 0..15
      const int co = ((g0 ^ (rl & 7)) << 4) + (hh & 1) * 8;
      u64 a0 = *(const u64*)(As + (sw * 32 + rl +  0) * 256 + co);
      u64 a1 = *(const u64*)(As + (sw * 32 + rl + 16) * 256 + co);
      u64 b0 = *(const u64*)(Bs + (rl +  0) * 256 + co);
      u64 b1 = *(const u64*)(Bs + (rl + 16) * 256 + co);
      __builtin_amdgcn_s_setprio(1);
      acc[0][0] = __builtin_amdgcn_mfma_f32_16x16x32_fp8_fp8((long)a0, (long)b0, acc[0][0], 0, 0, 0);
      acc[0][1] = __builtin_amdgcn_mfma_f32_16x16x32_fp8_fp8((long)a0, (long)b1, acc[0][1], 0, 0, 0);
      acc[1][0] = __builtin_amdgcn_mfma_f32_16x16x32_fp8_fp8((long)a1, (long)b0, acc[1][0], 0, 0, 0);
      acc[1][1] = __builtin_amdgcn_mfma_f32_16x16x32_fp8_fp8((long)a1, (long)b1, acc[1][1], 0, 0, 0);
      __builtin_amdgcn_s_setprio(0);
    }
  };

  stage(0, 0); stage(1, 1);
  int cur = 0, pre = 2;
  for (int t = 0; t < 16; ++t) {
    if (t < 15) {
      if (!isB) { asm volatile("s_waitcnt vmcnt(4)" ::: "memory"); }
      else      { asm volatile("s_waitcnt vmcnt(2)" ::: "memory"); }
    } else       { asm volatile("s_waitcnt vmcnt(0)" ::: "memory"); }
    __builtin_amdgcn_sched_barrier(0);
    __builtin_amdgcn_s_barrier();
    __builtin_amdgcn_sched_barrier(0);
    if (t + 2 < 16) stage(pre, t + 2);
    compute(cur);
    cur = (cur == 2) ? 0 : cur + 1;
    pre = (pre == 2) ? 0 : pre + 1;
  }
  __builtin_amdgcn_s_barrier();
  __builtin_amdgcn_sched_barrier(0);

  f32x4 o = ksplit_reduce(smem, acc, kw, sw, hh, rl);
  const int row0 = m0 + sw * 32 + (kw >> 1) * 16 + hh * 4;
  const int col  = n0 + (kw & 1) * 16 + rl;
  #pragma unroll
  for (int r = 0; r < 4; ++r)
    Cb[(row0 + r) * HID + col] = (bf16)(o[r] * 2.44140625e-4f);
}

// ---------------- bf16 GEMM: 64x32 tile, 2 blocks/CU ----------------
// KK==256: single-shot staging (whole K in LDS: A 32KB + B 16KB), one barrier.
// KK==512: 2-buf pipelined loop (EPI1 only).
// EPI: 1=tanh->bf16  2=h init (xs,traj0,Y8)  3..6=k1..k4 RK4  7=f32 out+bias
template<int EPI, int KK>
__global__ __launch_bounds__(512, 2) void gemmbf(
    const bf16* __restrict__ Ag, int lda,
    const bf16* __restrict__ Bg, int ldb,
    int Ntiles,
    const float* __restrict__ bias,
    float* __restrict__ outf,
    bf16* __restrict__ outb,
    u8* __restrict__ ybt,                 // fp8 y^T [HID][NN]
    float* __restrict__ xbuf,
    const float* __restrict__ kk1,
    const float* __restrict__ kk2,
    const float* __restrict__ kk3,
    const float* __restrict__ vt, int step)
{
  __shared__ __align__(16) char smem[49152];
  const int tid = threadIdx.x;
  const int l = tid & 63, wv = tid >> 6;
  const int kw = wv & 3, sw = wv >> 2;
  const int rl = l & 15, hh = l >> 4;

  const int chunk = gridDim.x >> 3;
  const int sb = (blockIdx.x & 7) * chunk + (blockIdx.x >> 3);
  const int mtile = sb / Ntiles;
  const int ntile = sb - mtile * Ntiles;
  const int m0 = mtile * 64, n0 = ntile * 32;

  const bool isB = wv >= 4;
  const int w4 = wv & 3;

  f32x4 acc[2][2];
  #pragma unroll
  for (int i = 0; i < 2; ++i)
    #pragma unroll
    for (int j = 0; j < 2; ++j) acc[i][j] = (f32x4){0.f, 0.f, 0.f, 0.f};

  if constexpr (KK == 256) {
    // ---- single-shot: LDS A [64][512B] @0, B [32][512B] @32768 (verified R8) ----
    const int lrow = l >> 5, lg = l & 31;
    if (!isB) {
      const char* gb = (const char*)(Ag + (size_t)(m0 + w4 * 16) * lda);
      char* base = smem + w4 * 8192;
      #pragma unroll
      for (int i = 0; i < 8; ++i) {
        const int r = i * 2 + lrow;                  // local row within 16
        const int swz = (lg ^ ((w4 * 16 + r) & 7)) << 4;
        gload16(gb + (size_t)r * lda * 2 + swz, base + i * 1024);
      }
    } else {
      const char* gb = (const char*)(Bg + (size_t)(n0 + w4 * 8) * ldb);
      char* base = smem + 32768 + w4 * 4096;
      #pragma unroll
      for (int i = 0; i < 4; ++i) {
        const int r = i * 2 + lrow;                  // local row within 8
        const int swz = (lg ^ ((w4 * 8 + r) & 7)) << 4;
        gload16(gb + (size_t)r * ldb * 2 + swz, base + i * 1024);
      }
    }
    asm volatile("s_waitcnt vmcnt(0)" ::: "memory");
    __builtin_amdgcn_sched_barrier(0);
    __builtin_amdgcn_s_barrier();
    __builtin_amdgcn_sched_barrier(0);

    const char* As = smem;
    const char* Bs = smem + 32768;
    #pragma unroll
    for (int ks = 0; ks < 2; ++ks) {
      const int ca = ((((kw * 2 + ks) * 4 + hh) ^ (rl & 7)) << 4);
      bf16x8 a0 = *(const bf16x8*)(As + (sw * 32 + rl +  0) * 512 + ca);
      bf16x8 a1 = *(const bf16x8*)(As + (sw * 32 + rl + 16) * 512 + ca);
      bf16x8 b0 = *(const bf16x8*)(Bs + (rl +  0) * 512 + ca);
      bf16x8 b1 = *(const bf16x8*)(Bs + (rl + 16) * 512 + ca);
      __builtin_amdgcn_s_setprio(1);
      acc[0][0] = __builtin_amdgcn_mfma_f32_16x16x32_bf16(a0, b0, acc[0][0], 0, 0, 0);
      acc[0][1] = __builtin_amdgcn_mfma_f32_16x16x32_bf16(a0, b1, acc[0][1], 0, 0, 0);
      acc[1][0] = __builtin_amdgcn_mfma_f32_16x16x32_bf16(a1, b0, acc[1][0], 0, 0, 0);
      acc[1][1] = __builtin_amdgcn_mfma_f32_16x16x32_bf16(a1, b1, acc[1][1], 0, 0, 0);
      __builtin_amdgcn_s_setprio(0);
    }
    __builtin_amdgcn_s_barrier();
    __builtin_amdgcn_sched_barrier(0);
  } else {
    // ---- pipelined 2-buf loop (macro 128 elems = 256B) ----
    const int rlo = l >> 4, gq = l & 15;
    const size_t ldby = (size_t)(isB ? ldb : lda) * 2;
    const int grow = (isB ? n0 + w4 * 8 : m0 + w4 * 16) + rlo;
    const char* sGb = (const char*)(isB ? (const void*)Bg : (const void*)Ag)
                      + (size_t)grow * ldby;
    const int c0 = (gq ^ rlo) << 4;
    const int c1 = (gq ^ (rlo + 4)) << 4;
    const int stoff = isB ? 16384 + w4 * 2048 : w4 * 4096;

    auto stage = [&](int buf, int t) {
      char* base = smem + buf * 24576 + stoff;
      const char* g = sGb + (size_t)t * 256;
      gload16(g + c0,            base);
      gload16(g + 4 * ldby + c1, base + 1024);
      if (!isB) {
        gload16(g +  8 * ldby + c0, base + 2048);
        gload16(g + 12 * ldby + c1, base + 3072);
      }
    };

    const int ca = ((kw * 4 + hh) ^ (rl & 7)) << 4;
    auto compute = [&](int buf) {
      const char* As = smem + buf * 24576;
      const char* Bs = As + 16384;
      bf16x8 a0 = *(const bf16x8*)(As + (sw * 32 + rl +  0) * 256 + ca);
      bf16x8 a1 = *(const bf16x8*)(As + (sw * 32 + rl + 16) * 256 + ca);
      bf16x8 b0 = *(const bf16x8*)(Bs + (rl +  0) * 256 + ca);
      bf16x8 b1 = *(const bf16x8*)(Bs + (rl + 16) * 256 + ca);
      __builtin_amdgcn_s_setprio(1);
      acc[0][0] = __builtin_amdgcn_mfma_f32_16x16x32_bf16(a0, b0, acc[0][0], 0, 0, 0);
      acc[0][1] = __builtin_amdgcn_mfma_f32_16x16x32_bf16(a0, b1, acc[0][1], 0, 0, 0);
      acc[1][0] = __builtin_amdgcn_mfma_f32_16x16x32_bf16(a1, b0, acc[1][0], 0, 0, 0);
      acc[1][1] = __builtin_amdgcn_mfma_f32_16x16x32_bf16(a1, b1, acc[1][1], 0, 0, 0);
      __builtin_amdgcn_s_setprio(0);
    };

    const int nmac = KK >> 7;
    stage(0, 0);
    asm volatile("s_waitcnt vmcnt(0)" ::: "memory");
    __builtin_amdgcn_s_barrier();
    int cur = 0;
    for (int t = 0; t < nmac; ++t) {
      if (t + 1 < nmac) stage(cur ^ 1, t + 1);
      compute(cur);
      asm volatile("s_waitcnt vmcnt(0)" ::: "memory");
      __builtin_amdgcn_sched_barrier(0);
      __builtin_amdgcn_s_barrier();
      cur ^= 1;
    }
    __builtin_amdgcn_sched_barrier(0);
  }

  f32x4 o = ksplit_reduce(smem, acc, kw, sw, hh, rl);
  const int row0 = m0 + sw * 32 + (kw >> 1) * 16 + hh * 4;
  const int col  = n0 + (kw & 1) * 16 + rl;

  float dtv = 0.f;
  if constexpr (EPI >= 3 && EPI <= 6) dtv = vt[step + 1] - vt[step];

  if constexpr (EPI == 1) {
    #pragma unroll
    for (int r = 0; r < 4; ++r)
      outb[(row0 + r) * HID + col] = (bf16)tanhf(o[r] + bias[col]);
  } else if constexpr (EPI == 2) {
    float yv[4];
    #pragma unroll
    for (int r = 0; r < 4; ++r) {
      float v = o[r] + bias[col];
      xbuf[(row0 + r) * HID + col] = v;
      outb[(row0 + r) * HID + col] = (bf16)v;
      yv[r] = v;
    }
    u32 pk = __builtin_amdgcn_cvt_pk_fp8_f32(yv[0], yv[1], 0, false);
    pk = __builtin_amdgcn_cvt_pk_fp8_f32(yv[2], yv[3], pk, true);
    *(u32*)(ybt + (size_t)col * NN + row0) = pk;
  } else if constexpr (EPI >= 3 && EPI <= 6) {
    float yv[4];
    #pragma unroll
    for (int r = 0; r < 4; ++r) {
      const int idx = (row0 + r) * HID + col;
      float v = fmaxf(o[r] + bias[col], 0.f);   // k_p
      float xv = xbuf[idx];
      float y;
      if constexpr (EPI == 3)      { outf[idx] = v; y = xv + dtv * (1.f/3.f) * v; }
      else if constexpr (EPI == 4) { outf[idx] = v; y = xv + dtv * (v - kk1[idx] * (1.f/3.f)); }
      else if constexpr (EPI == 5) { outf[idx] = v; y = xv + dtv * (kk1[idx] - kk2[idx] + v); }
      else {
        float xn = xv + dtv * 0.125f * (kk1[idx] + 3.f*kk2[idx] + 3.f*kk3[idx] + v);
        xbuf[idx] = xn;
        outb[idx] = (bf16)xn;   // traj slot t+1
        y = xn;
      }
      yv[r] = y;
    }
    u32 pk = __builtin_amdgcn_cvt_pk_fp8_f32(yv[0], yv[1], 0, false);
    pk = __builtin_amdgcn_cvt_pk_fp8_f32(yv[2], yv[3], pk, true);
    *(u32*)(ybt + (size_t)col * NN + row0) = pk;
  } else { // EPI == 7
    #pragma unroll
    for (int r = 0; r < 4; ++r)
      outf[(size_t)(row0 + r) * NCLS + col] = o[r] + bias[col];
  }
}

extern "C" void kernel_launch(void* const* d_in, const int* in_sizes, int n_in,
                              void* d_out, int out_size, void* d_ws, size_t ws_size,
                              hipStream_t stream)
{
  const float* vt = (const float*)d_in[0];
  const float* x  = (const float*)d_in[1];
  const float* A  = (const float*)d_in[2];
  const float* W1 = (const float*)d_in[3];
  const float* b1 = (const float*)d_in[4];
  const float* W2 = (const float*)d_in[5];
  const float* b2 = (const float*)d_in[6];
  const float* Wt = (const float*)d_in[7];
  const float* bt = (const float*)d_in[8];
  const float* Wo = (const float*)d_in[9];
  const float* bo = (const float*)d_in[10];
  float* out = (float*)d_out;

  char* p = (char*)d_ws;
  auto carve = [&](size_t n) { char* r = p; p += (n + 255) & ~(size_t)255; return r; };
  u8*   A8  = (u8*)carve((size_t)4096 * 4096);        // fp8 A * 2^12
  bf16* xb  = (bf16*)carve((size_t)4096 * 512 * 2);
  bf16* W1b = (bf16*)carve((size_t)256 * 512 * 2);
  bf16* W2b = (bf16*)carve((size_t)256 * 256 * 2);
  bf16* Wtb = (bf16*)carve((size_t)256 * 256 * 2);
  bf16* Wob = (bf16*)carve((size_t)128 * 256 * 2);
  bf16* T1b = (bf16*)carve((size_t)4096 * 256 * 2);
  bf16* Cb  = (bf16*)carve((size_t)4096 * 256 * 2);
  u8*   Y8  = (u8*)carve((size_t)256 * 4096);         // fp8 y^T [HID][NN]
  float* xs = (float*)carve((size_t)4096 * 256 * 4);
  float* k1 = (float*)carve((size_t)4096 * 256 * 4);
  float* k2 = (float*)carve((size_t)4096 * 256 * 4);
  float* k3 = (float*)carve((size_t)4096 * 256 * 4);
  size_t base_need = (size_t)(p - (char*)d_ws);
  const size_t trajBytes = (size_t)20 * 4096 * 256 * 2;
  bool big = (ws_size >= base_need + trajBytes);
  bf16* traj = (bf16*)carve(big ? trajBytes : (size_t)4096 * 256 * 2);

  convAf8<<<16384, 256, 0, stream>>>(A,  A8,  16777216);
  convf2b<<<2048,  256, 0, stream>>>(x,  xb,  2097152);
  convf2b<<<128,   256, 0, stream>>>(W1, W1b, 131072);
  convf2b<<<64,    256, 0, stream>>>(W2, W2b, 65536);
  convf2b<<<64,    256, 0, stream>>>(Wt, Wtb, 65536);
  convf2b<<<32,    256, 0, stream>>>(Wo, Wob, 32768);

  gemmbf<1, 512><<<512, 512, 0, stream>>>(xb, 512, W1b, 512, 8, b1,
      nullptr, T1b, nullptr, nullptr, nullptr, nullptr, nullptr, vt, 0);
  gemmbf<2, 256><<<512, 512, 0, stream>>>(T1b, 256, W2b, 256, 8, b2,
      nullptr, traj, Y8, xs, nullptr, nullptr, nullptr, vt, 0);
  if (!big)
    gemmbf<7, 256><<<256, 512, 0, stream>>>(traj, 256, Wob, 256, 4, bo,
        out, nullptr, nullptr, nullptr, nullptr, nullptr, nullptr, vt, 0);

  for (int t = 0; t < 19; ++t) {
    bf16* slot = big ? (traj + (size_t)(t + 1) * 4096 * 256) : traj;
    gemmf8<<<512, 512, 0, stream>>>(A8, Y8, Cb);
    gemmbf<3, 256><<<512, 512, 0, stream>>>(Cb, 256, Wtb, 256, 8, bt,
        k1, nullptr, Y8, xs, nullptr, nullptr, nullptr, vt, t);
    gemmf8<<<512, 512, 0, stream>>>(A8, Y8, Cb);
    gemmbf<4, 256><<<512, 512, 0, stream>>>(Cb, 256, Wtb, 256, 8, bt,
        k2, nullptr, Y8, xs, k1, nullptr, nullptr, vt, t);
    gemmf8<<<512, 512, 0, stream>>>(A8, Y8, Cb);
    gemmbf<5, 256><<<512, 512, 0, stream>>>(Cb, 256, Wtb, 256, 8, bt,
        k3, nullptr, Y8, xs, k1, k2, nullptr, vt, t);
    gemmf8<<<512, 512, 0, stream>>>(A8, Y8, Cb);
    gemmbf<6, 256><<<512, 512, 0, stream>>>(Cb, 256, Wtb, 256, 8, bt,
        nullptr, slot, Y8, xs, k1, k2, k3, vt, t);
    if (!big)
      gemmbf<7, 256><<<256, 512, 0, stream>>>(traj, 256, Wob, 256, 4, bo,
          out + (size_t)(t + 1) * 4096 * 128, nullptr, nullptr, nullptr,
          nullptr, nullptr, nullptr, vt, 0);
  }
  if (big)
    gemmbf<7, 256><<<5120, 512, 0, stream>>>(traj, 256, Wob, 256, 4, bo,
        out, nullptr, nullptr, nullptr, nullptr, nullptr, nullptr, vt, 0);
}